// Round 4
// baseline (482.815 us; speedup 1.0000x reference)
//
#include <hip/hip_runtime.h>
#include <hip/hip_bf16.h>

// Problem constants (fixed by the reference)
constexpr int N_NODES = 50000;
constexpr int N_EDGES = 800000;
constexpr int R_REL   = 8;
constexpr int BASES   = 4;
constexpr int D       = 256;                 // DIN = DH = DOUT
constexpr int KZ      = BASES * D;           // 1024: basis-space aggregate
constexpr int KT      = KZ + D;              // 1280: + self block
constexpr int WSTRIDE = 16;                  // wtab float4s per node (r=8 is the
                                             // zero-weight dummy slot)
constexpr int DUMMY_P = 8 << 20;             // dummy edge: src=0, rel=8

// grid geometry
constexpr int EB  = (N_EDGES + 255) / 256;        // 3125 (bucket)
constexpr int EB4 = (N_EDGES + 1023) / 1024;      // 782  (count, 4 edges/thread)
constexpr int NB  = (N_NODES + 255) / 256;        // 196
constexpr int CB4 = (N_NODES * 128) / 1024;       // 6250 (exact; 4 uints/thread)
constexpr int WKB = KT / 64;                      // 20 (make_w blocks per layer)
constexpr int WB  = (N_NODES * WSTRIDE) / 256;    // 3125 (exact)
constexpr int CAP = N_EDGES + N_NODES * 8;        // 1,200,000 padded edge cap
constexpr int FB4 = (CAP + 1023) / 1024;          // 1172 (4 ints/thread)

typedef __attribute__((ext_vector_type(8))) short bf16x8;
typedef __attribute__((ext_vector_type(4))) float f32x4;

__device__ inline float bfu_lo(unsigned u) { return __uint_as_float(u << 16); }
__device__ inline float bfu_hi(unsigned u) { return __uint_as_float(u & 0xFFFF0000u); }
__device__ inline unsigned short f2bu(float f) {
  __hip_bfloat16 h = __float2bfloat16(f);
  return *reinterpret_cast<unsigned short*>(&h);
}
__device__ inline void store_out(float* p, float v) { *p = v; }
__device__ inline void store_out(__hip_bfloat16* p, float v) { *p = __float2bfloat16(v); }

// async 16B global -> LDS (wave-uniform lds base + lane*16)
__device__ inline void gload_lds16(void* lds, const void* g) {
  __builtin_amdgcn_global_load_lds(
      (const __attribute__((address_space(1))) unsigned*)g,
      (__attribute__((address_space(3))) unsigned*)lds, 16, 0, 0);
}

// ---------------------------------------------------------------------------
// 1. Fused prep: [count | convert x->bf16 | make_w x2 | dummy-fill packed]
//    All jobs independent; range-split on blockIdx.
//    Round-4 fixes: 8 KB LDS (was 32 KB -> capped ALL blocks at 5/CU);
//    4 elements/thread for count/convert/fill (was 1 -> latency-exposed).
// ---------------------------------------------------------------------------
__global__ __launch_bounds__(256) void prep_kernel(
    const int* __restrict__ ei, const int* __restrict__ et,
    int* __restrict__ cnt,
    const float* __restrict__ x, unsigned* __restrict__ x2,
    const float* __restrict__ basis1, const float* __restrict__ root1,
    __hip_bfloat16* __restrict__ WT1,
    const float* __restrict__ basis2, const float* __restrict__ root2,
    __hip_bfloat16* __restrict__ WT2,
    int* __restrict__ packed) {
  __shared__ __hip_bfloat16 tile[16][256];   // 8 KB
  int bid = blockIdx.x;
  int tid = threadIdx.x;

  if (bid < EB4) {                      // --- count (4 edges/thread) ---
    int e4 = (bid * 256 + tid) * 4;
    if (e4 < N_EDGES) {                 // N_EDGES % 4 == 0 -> full int4 valid
      int4 dv = *(const int4*)(ei + N_EDGES + e4);
      int4 tv = *(const int4*)(et + e4);
      atomicAdd(&cnt[dv.x * R_REL + tv.x], 1);
      atomicAdd(&cnt[dv.y * R_REL + tv.y], 1);
      atomicAdd(&cnt[dv.z * R_REL + tv.z], 1);
      atomicAdd(&cnt[dv.w * R_REL + tv.w], 1);
    }
    return;
  }
  bid -= EB4;
  if (bid < CB4) {                      // --- convert x -> bf16 (4 uints/thr) ---
    int idx = (bid * 256 + tid) * 4;    // exact: CB4*1024 == N*128
    const float* px = x + (size_t)idx * 2;
    float4 a = *(const float4*)(px);
    float4 b = *(const float4*)(px + 4);
    uint4 o;
    o.x = (unsigned)f2bu(a.x) | ((unsigned)f2bu(a.y) << 16);
    o.y = (unsigned)f2bu(a.z) | ((unsigned)f2bu(a.w) << 16);
    o.z = (unsigned)f2bu(b.x) | ((unsigned)f2bu(b.y) << 16);
    o.w = (unsigned)f2bu(b.z) | ((unsigned)f2bu(b.w) << 16);
    *(uint4*)(x2 + idx) = o;
    return;
  }
  bid -= CB4;
  if (bid < 2 * WKB) {                  // --- weight build (both layers) ---
    const float* basis = (bid < WKB) ? basis1 : basis2;
    const float* root  = (bid < WKB) ? root1 : root2;
    __hip_bfloat16* WT = (bid < WKB) ? WT1 : WT2;
    int wb = (bid < WKB) ? bid : bid - WKB;
    int k0 = wb * 64;
#pragma unroll
    for (int pass = 0; pass < 4; pass++) {
      int kp = k0 + pass * 16;
#pragma unroll
      for (int r = 0; r < 16; r++) {
        int k = kp + r;
        const float* srow = (k < KZ)
            ? basis + ((size_t)(k & 3) * D + (k >> 2)) * D
            : root + (size_t)(k - KZ) * D;
        tile[r][tid] = __float2bfloat16(srow[tid]);
      }
      __syncthreads();
      __hip_bfloat16* dst = WT + (size_t)tid * KT + kp;
#pragma unroll
      for (int c = 0; c < 2; c++) {
        union { short s[8]; int4 v; } u;
#pragma unroll
        for (int r = 0; r < 8; r++)
          u.s[r] = *reinterpret_cast<short*>(&tile[c * 8 + r][tid]);
        *(int4*)(dst + c * 8) = u.v;
      }
      __syncthreads();
    }
    return;
  }
  bid -= 2 * WKB;
  {                                     // --- dummy-fill packed (4 ints/thr) ---
    int i = (bid * 256 + tid) * 4;
    if (i < CAP) {                      // CAP % 4 == 0 -> full int4 valid
      int4 f = make_int4(DUMMY_P, DUMMY_P, DUMMY_P, DUMMY_P);
      *(int4*)(packed + i) = f;
    }
  }
}

// ---------------------------------------------------------------------------
// 2. scanA (block sums of PADDED degree) fused with winv x2
// ---------------------------------------------------------------------------
__global__ __launch_bounds__(256) void scanA_winv_kernel(
    const int* __restrict__ cnt, int* __restrict__ bsum,
    const float* __restrict__ comp1, float4* __restrict__ wtab1,
    const float* __restrict__ comp2, float4* __restrict__ wtab2) {
  __shared__ int sd[256];
  int bid = blockIdx.x;
  int tid = threadIdx.x;
  if (bid < NB) {                       // --- scanA on padded degree ---
    int n = bid * 256 + tid;
    int d = 0;
    if (n < N_NODES) {
#pragma unroll
      for (int r = 0; r < R_REL; r++) d += cnt[n * R_REL + r];
      d = (d + 7) & ~7;                 // pad each bucket to x8
    }
    sd[tid] = d;
    __syncthreads();
    for (int off = 128; off > 0; off >>= 1) {
      if (tid < off) sd[tid] += sd[tid + off];
      __syncthreads();
    }
    if (tid == 0) bsum[bid] = sd[0];
    return;
  }
  bid -= NB;
  {                                     // --- winv (both layers) ---
    const float* comp = (bid < WB) ? comp1 : comp2;
    float4* wtab = (bid < WB) ? wtab1 : wtab2;
    int lb = (bid < WB) ? bid : bid - WB;
    int idx = lb * 256 + tid;           // exact: WB*256 == N*WSTRIDE
    int r = idx & (WSTRIDE - 1);
    int n = idx >> 4;
    float4 w = make_float4(0.f, 0.f, 0.f, 0.f);
    if (r < R_REL) {
      int c = cnt[n * R_REL + r];
      float inv = 1.0f / (float)(c > 0 ? c : 1);
      w.x = comp[r * BASES + 0] * inv;
      w.y = comp[r * BASES + 1] * inv;
      w.z = comp[r * BASES + 2] * inv;
      w.w = comp[r * BASES + 3] * inv;
    }
    wtab[idx] = w;
  }
}

// ---------------------------------------------------------------------------
// 3. Scan phases B/C on padded degree. scanC also zeroes cursor.
// ---------------------------------------------------------------------------
__global__ __launch_bounds__(256) void scan_phaseB(
    const int* __restrict__ bsum, int* __restrict__ boff,
    int* __restrict__ estart) {
  __shared__ int sd[256];
  int tid = threadIdx.x;
  int v = (tid < NB) ? bsum[tid] : 0;
  sd[tid] = v;
  __syncthreads();
  for (int off = 1; off < 256; off <<= 1) {
    int t = (tid >= off) ? sd[tid - off] : 0;
    __syncthreads();
    sd[tid] += t;
    __syncthreads();
  }
  if (tid < NB) boff[tid] = sd[tid] - v;
  if (tid == NB - 1) estart[N_NODES] = sd[tid];   // total padded edges
}

__global__ __launch_bounds__(256) void scan_phaseC(
    const int* __restrict__ cnt, const int* __restrict__ boff,
    int* __restrict__ estart, int* __restrict__ cursor) {
  __shared__ int sd[256];
  int tid = threadIdx.x;
  int n = blockIdx.x * 256 + tid;
  int d = 0;
  if (n < N_NODES) {
#pragma unroll
    for (int r = 0; r < R_REL; r++) d += cnt[n * R_REL + r];
    d = (d + 7) & ~7;
  }
  sd[tid] = d;
  __syncthreads();
  for (int off = 1; off < 256; off <<= 1) {
    int t = (tid >= off) ? sd[tid - off] : 0;
    __syncthreads();
    sd[tid] += t;
    __syncthreads();
  }
  if (n < N_NODES) {
    estart[n] = boff[blockIdx.x] + sd[tid] - d;
    cursor[n] = 0;
  }
}

// ---------------------------------------------------------------------------
// 4. Bucket edges by dst into padded layout: packed = src | (rt << 20).
//    Tail of each bucket stays DUMMY_P (prefilled).
// ---------------------------------------------------------------------------
__global__ __launch_bounds__(256) void bucket_kernel(
    const int* __restrict__ ei, const int* __restrict__ et,
    const int* __restrict__ estart, int* __restrict__ cursor,
    int* __restrict__ packed) {
  int e = blockIdx.x * 256 + threadIdx.x;
  if (e < N_EDGES) {
    int src = ei[e];
    int dst = ei[N_EDGES + e];
    int rt  = et[e];
    int pos = estart[dst] + atomicAdd(&cursor[dst], 1);
    packed[pos] = src | (rt << 20);
  }
}

// ---------------------------------------------------------------------------
// 5. Aggregate into basis space. WAVE per node (4/block). All wave-uniform
//    work (edge list, weights, row bases) forced onto the SCALAR pipe via
//    readfirstlane; buckets padded to x8 so the inner loop is branch- and
//    mask-free. Per-edge vector work: 1 global_load_dwordx2 (loop-invariant
//    voff), 4 unpack ops, 8 pk-fma.
// ---------------------------------------------------------------------------
__device__ inline float2 pfma(float s, float2 a, float2 c) {
  c.x = fmaf(s, a.x, c.x);
  c.y = fmaf(s, a.y, c.y);
  return c;
}

__device__ inline void edge_fma(float2 acc[BASES][2], uint2 v, float4 w) {
  float2 a01 = make_float2(bfu_lo(v.x), bfu_hi(v.x));
  float2 a23 = make_float2(bfu_lo(v.y), bfu_hi(v.y));
  acc[0][0] = pfma(w.x, a01, acc[0][0]); acc[0][1] = pfma(w.x, a23, acc[0][1]);
  acc[1][0] = pfma(w.y, a01, acc[1][0]); acc[1][1] = pfma(w.y, a23, acc[1][1]);
  acc[2][0] = pfma(w.z, a01, acc[2][0]); acc[2][1] = pfma(w.z, a23, acc[2][1]);
  acc[3][0] = pfma(w.w, a01, acc[3][0]); acc[3][1] = pfma(w.w, a23, acc[3][1]);
}

__global__ __launch_bounds__(256) void aggregate_kernel(
    const unsigned* __restrict__ x2,   // bf16 features as uint pairs [N][128]
    const int* __restrict__ packed,    // padded-x8 buckets
    const int* __restrict__ estart,    // padded offsets
    const float4* __restrict__ wtab,   // [N*16]; slot 8 = zero (dummy)
    __hip_bfloat16* __restrict__ zA)   // [N][KZ]
{
  int tid = threadIdx.x;
  int lane = tid & 63;
  int n = __builtin_amdgcn_readfirstlane(blockIdx.x * 4 + (tid >> 6));
  int s = __builtin_amdgcn_readfirstlane(estart[n]);
  int e = __builtin_amdgcn_readfirstlane(estart[n + 1]);
  const int voff = lane * 2;                         // uint index within row
  const float4* wt = wtab + (size_t)n * WSTRIDE;

  float2 acc[BASES][2] = {};

  for (int base = s; base < e; base += 8) {
    int4 q0 = *(const int4*)(packed + base);         // uniform addr -> s_load
    int4 q1 = *(const int4*)(packed + base + 4);
    int p0 = __builtin_amdgcn_readfirstlane(q0.x);
    int p1 = __builtin_amdgcn_readfirstlane(q0.y);
    int p2 = __builtin_amdgcn_readfirstlane(q0.z);
    int p3 = __builtin_amdgcn_readfirstlane(q0.w);
    int p4 = __builtin_amdgcn_readfirstlane(q1.x);
    int p5 = __builtin_amdgcn_readfirstlane(q1.y);
    int p6 = __builtin_amdgcn_readfirstlane(q1.z);
    int p7 = __builtin_amdgcn_readfirstlane(q1.w);
    // SGPR row bases; vector part is just base+voff
    const unsigned* r0 = x2 + ((size_t)(p0 & 0xFFFFF) << 7);
    const unsigned* r1 = x2 + ((size_t)(p1 & 0xFFFFF) << 7);
    const unsigned* r2 = x2 + ((size_t)(p2 & 0xFFFFF) << 7);
    const unsigned* r3 = x2 + ((size_t)(p3 & 0xFFFFF) << 7);
    const unsigned* r4 = x2 + ((size_t)(p4 & 0xFFFFF) << 7);
    const unsigned* r5 = x2 + ((size_t)(p5 & 0xFFFFF) << 7);
    const unsigned* r6 = x2 + ((size_t)(p6 & 0xFFFFF) << 7);
    const unsigned* r7 = x2 + ((size_t)(p7 & 0xFFFFF) << 7);
    uint2 v0 = *(const uint2*)(r0 + voff);
    uint2 v1 = *(const uint2*)(r1 + voff);
    uint2 v2 = *(const uint2*)(r2 + voff);
    uint2 v3 = *(const uint2*)(r3 + voff);
    uint2 v4 = *(const uint2*)(r4 + voff);
    uint2 v5 = *(const uint2*)(r5 + voff);
    uint2 v6 = *(const uint2*)(r6 + voff);
    uint2 v7 = *(const uint2*)(r7 + voff);
    float4 w0 = wt[p0 >> 20];                        // uniform -> s_load_x4
    float4 w1 = wt[p1 >> 20];
    float4 w2 = wt[p2 >> 20];
    float4 w3 = wt[p3 >> 20];
    float4 w4 = wt[p4 >> 20];
    float4 w5 = wt[p5 >> 20];
    float4 w6 = wt[p6 >> 20];
    float4 w7 = wt[p7 >> 20];
    edge_fma(acc, v0, w0);
    edge_fma(acc, v1, w1);
    edge_fma(acc, v2, w2);
    edge_fma(acc, v3, w3);
    edge_fma(acc, v4, w4);
    edge_fma(acc, v5, w5);
    edge_fma(acc, v6, w6);
    edge_fma(acc, v7, w7);
  }

  // store: k = (4*lane+j)*4 + b = 16*lane + 4*j + b -> 32 contiguous bytes
  union { short s[8]; int4 v; } u0, u1;
#pragma unroll
  for (int b = 0; b < BASES; b++) {
    u0.s[b]     = (short)f2bu(acc[b][0].x);
    u0.s[4 + b] = (short)f2bu(acc[b][0].y);
    u1.s[b]     = (short)f2bu(acc[b][1].x);
    u1.s[4 + b] = (short)f2bu(acc[b][1].y);
  }
  __hip_bfloat16* zrow = zA + (size_t)n * KZ;
  *(int4*)(zrow + 16 * lane) = u0.v;
  *(int4*)(zrow + 16 * lane + 8) = u1.v;
}

// ---------------------------------------------------------------------------
// 6. GEMM: C[M,256] = A[M,1280](bf16) @ WT^T + bias. BM=128, BN=256 (full N,
//    A read once), 512 threads / 8 waves, BK=32, global_load_lds staging.
//    A split: k<1024 from Az ([M][1024] aggregate), k>=1024 from Aself.
// ---------------------------------------------------------------------------
#define BM 128
#define BN 256
#define BK 32

template <bool RELU, typename OutT>
__global__ __launch_bounds__(512) void gemm_kernel(
    const __hip_bfloat16* __restrict__ Az,     // [M, KZ]
    const __hip_bfloat16* __restrict__ Aself,  // [M, D]
    const __hip_bfloat16* __restrict__ Bt,     // [256, KT]
    const float* __restrict__ bias, OutT* __restrict__ C, int M) {
  __shared__ __align__(16) __hip_bfloat16 As[BM * BK];  // 8 KB
  __shared__ __align__(16) __hip_bfloat16 Bs[BN * BK];  // 16 KB
  int tid = threadIdx.x;
  int m0 = blockIdx.x * BM;
  int wave = tid >> 6, lane = tid & 63;
  int wm = wave & 1, wn = wave >> 1;   // 2 x 4 wave grid, 64x64 tiles
  int l15 = lane & 15, quad = lane >> 4;

  int colS = (lane & 3) * 8;
  int rowA = wave * 16 + (lane >> 2);           // 0..127 across 8 waves
  int grA  = min(m0 + rowA, M - 1);             // clamp; epilogue masks tail
  const __hip_bfloat16* gAz = Az + (size_t)grA * KZ + colS;
  const __hip_bfloat16* gAs = Aself + (size_t)grA * D + colS;
  const __hip_bfloat16* gB0 = Bt + (size_t)(wave * 32 + (lane >> 2)) * KT + colS;
  const __hip_bfloat16* gB1 = gB0 + 16 * KT;
  __hip_bfloat16* lA  = As + wave * 512;
  __hip_bfloat16* lB0 = Bs + wave * 1024;
  __hip_bfloat16* lB1 = Bs + wave * 1024 + 512;

  f32x4 acc[4][4] = {};

  for (int k0 = 0; k0 < KT; k0 += BK) {
    const __hip_bfloat16* srcA = (k0 < KZ) ? (gAz + k0) : (gAs + (k0 - KZ));
    gload_lds16(lA, srcA);
    gload_lds16(lB0, gB0 + k0);
    gload_lds16(lB1, gB1 + k0);
    __syncthreads();

    bf16x8 af[4], bfr[4];
#pragma unroll
    for (int mt = 0; mt < 4; mt++)
      af[mt] = *(const bf16x8*)(As + (wm * 64 + mt * 16 + l15) * BK + quad * 8);
#pragma unroll
    for (int nt = 0; nt < 4; nt++)
      bfr[nt] = *(const bf16x8*)(Bs + (wn * 64 + nt * 16 + l15) * BK + quad * 8);
#pragma unroll
    for (int mt = 0; mt < 4; mt++)
#pragma unroll
      for (int nt = 0; nt < 4; nt++)
        acc[mt][nt] = __builtin_amdgcn_mfma_f32_16x16x32_bf16(
            af[mt], bfr[nt], acc[mt][nt], 0, 0, 0);
    __syncthreads();
  }

  // epilogue: C/D layout col = lane&15, row = quad*4 + reg
#pragma unroll
  for (int nt = 0; nt < 4; nt++) {
    int cg = wn * 64 + nt * 16 + l15;
    float bv = bias[cg];
#pragma unroll
    for (int mt = 0; mt < 4; mt++) {
#pragma unroll
      for (int r = 0; r < 4; r++) {
        int rg = m0 + wm * 64 + mt * 16 + quad * 4 + r;
        if (rg < M) {
          float v = acc[mt][nt][r] + bv;
          if (RELU) v = fmaxf(v, 0.f);
          store_out(C + (size_t)rg * D + cg, v);
        }
      }
    }
  }
}

// ---------------------------------------------------------------------------
// Launch
// ---------------------------------------------------------------------------
static inline char* carve(char*& p, size_t bytes) {
  char* r = p;
  p += (bytes + 255) & ~(size_t)255;
  return r;
}

extern "C" void kernel_launch(void* const* d_in, const int* in_sizes, int n_in,
                              void* d_out, int out_size, void* d_ws,
                              size_t ws_size, hipStream_t stream) {
  const float* x      = (const float*)d_in[0];
  const int*   ei     = (const int*)d_in[1];
  const int*   et     = (const int*)d_in[2];
  const float* basis1 = (const float*)d_in[3];
  const float* comp1  = (const float*)d_in[4];
  const float* root1  = (const float*)d_in[5];
  const float* bias1  = (const float*)d_in[6];
  const float* basis2 = (const float*)d_in[7];
  const float* comp2  = (const float*)d_in[8];
  const float* root2  = (const float*)d_in[9];
  const float* bias2  = (const float*)d_in[10];
  float* out = (float*)d_out;

  char* ws = (char*)d_ws;
  int* cnt    = (int*)carve(ws, (size_t)N_NODES * R_REL * 4);
  int* estart = (int*)carve(ws, (size_t)(N_NODES + 1) * 4);
  int* cursor = (int*)carve(ws, (size_t)N_NODES * 4);
  int* bsum   = (int*)carve(ws, 256 * 4);
  int* boff   = (int*)carve(ws, 256 * 4);
  int* packed = (int*)carve(ws, (size_t)CAP * 4);
  float4* wtab1 = (float4*)carve(ws, (size_t)N_NODES * WSTRIDE * 16);
  float4* wtab2 = (float4*)carve(ws, (size_t)N_NODES * WSTRIDE * 16);
  __hip_bfloat16* WT1 = (__hip_bfloat16*)carve(ws, (size_t)D * KT * 2);
  __hip_bfloat16* WT2 = (__hip_bfloat16*)carve(ws, (size_t)D * KT * 2);
  unsigned* xb = (unsigned*)carve(ws, (size_t)N_NODES * D * 2);   // bf16 x
  __hip_bfloat16* h = (__hip_bfloat16*)carve(ws, (size_t)N_NODES * D * 2);
  __hip_bfloat16* zA = (__hip_bfloat16*)carve(ws, (size_t)N_NODES * KZ * 2);

  hipMemsetAsync(cnt, 0, (size_t)N_NODES * R_REL * 4, stream);

  prep_kernel<<<EB4 + CB4 + 2 * WKB + FB4, 256, 0, stream>>>(
      ei, et, cnt, x, xb, basis1, root1, WT1, basis2, root2, WT2, packed);
  scanA_winv_kernel<<<NB + 2 * WB, 256, 0, stream>>>(cnt, bsum, comp1, wtab1,
                                                     comp2, wtab2);
  scan_phaseB<<<1, 256, 0, stream>>>(bsum, boff, estart);
  scan_phaseC<<<NB, 256, 0, stream>>>(cnt, boff, estart, cursor);
  bucket_kernel<<<EB, 256, 0, stream>>>(ei, et, estart, cursor, packed);

  dim3 ggrid((N_NODES + BM - 1) / BM, 1);  // 391 blocks, full N per block
  const int AB = (N_NODES + 3) / 4;        // 12500 blocks, wave per node

  // Layer 1
  aggregate_kernel<<<AB, 256, 0, stream>>>(xb, packed, estart, wtab1, zA);
  gemm_kernel<true, __hip_bfloat16><<<ggrid, 512, 0, stream>>>(
      zA, (const __hip_bfloat16*)xb, WT1, bias1, h, N_NODES);

  // Layer 2 (h is bf16 [N][256] — same packed-uint view as xb)
  aggregate_kernel<<<AB, 256, 0, stream>>>((const unsigned*)h, packed, estart,
                                           wtab2, zA);
  gemm_kernel<false, float><<<ggrid, 512, 0, stream>>>(
      zA, h, WT2, bias2, out, N_NODES);
}

// Round 5
// 443.923 us; speedup vs baseline: 1.0876x; 1.0876x over previous
//
#include <hip/hip_runtime.h>
#include <hip/hip_bf16.h>

// Problem constants (fixed by the reference)
constexpr int N_NODES = 50000;
constexpr int N_EDGES = 800000;
constexpr int R_REL   = 8;
constexpr int BASES   = 4;
constexpr int D       = 256;                 // DIN = DH = DOUT
constexpr int KZ      = BASES * D;           // 1024: basis-space aggregate
constexpr int KT      = KZ + D;              // 1280: + self block
constexpr int WSTRIDE = 16;                  // wtab float4s per node (r=8 is the
                                             // zero-weight dummy slot)
constexpr int DUMMY_P = 8 << 20;             // dummy edge: src=0, rel=8

// Sort geometry: coarse bucket = 256 consecutive dst nodes.
constexpr int NHI    = (N_NODES + 255) / 256;   // 196 coarse buckets
constexpr int NS_BLK = 200;                     // coarse-pass blocks
constexpr int CH     = N_EDGES / NS_BLK;        // 4000 edges/block (exact)

// grid geometry
constexpr int NB  = (N_NODES + 255) / 256;        // 196
constexpr int CB4 = (N_NODES * 128) / 1024;       // 6250 (exact; 4 uints/thread)
constexpr int WKB = KT / 64;                      // 20 (make_w blocks per layer)
constexpr int WB  = (N_NODES * WSTRIDE) / 256;    // 3125 (exact)
constexpr int CAP = N_EDGES + N_NODES * 8;        // 1,200,000 padded edge cap
constexpr int FB4 = (CAP + 1023) / 1024;          // 1172 (4 ints/thread)

typedef __attribute__((ext_vector_type(8))) short bf16x8;
typedef __attribute__((ext_vector_type(4))) float f32x4;

__device__ inline float bfu_lo(unsigned u) { return __uint_as_float(u << 16); }
__device__ inline float bfu_hi(unsigned u) { return __uint_as_float(u & 0xFFFF0000u); }
__device__ inline unsigned short f2bu(float f) {
  __hip_bfloat16 h = __float2bfloat16(f);
  return *reinterpret_cast<unsigned short*>(&h);
}
__device__ inline void store_out(float* p, float v) { *p = v; }
__device__ inline void store_out(__hip_bfloat16* p, float v) { *p = __float2bfloat16(v); }

// async 16B global -> LDS (wave-uniform lds base + lane*16)
__device__ inline void gload_lds16(void* lds, const void* g) {
  __builtin_amdgcn_global_load_lds(
      (const __attribute__((address_space(1))) unsigned*)g,
      (__attribute__((address_space(3))) unsigned*)lds, 16, 0, 0);
}

// ---------------------------------------------------------------------------
// 1. Fused prep: [coarse-hist P1 | convert x->bf16 | make_w x2 | dummy-fill]
//    Round-5: count/bucket's 800K device-scope atomics (memory-side RMW,
//    ~4/clk ceiling -> ~84us each) replaced by an LDS-histogram counting
//    sort. P1 here uses LDS atomics + <=196 global atomics per block.
// ---------------------------------------------------------------------------
__global__ __launch_bounds__(256) void prep_kernel(
    const int* __restrict__ ei, const int* __restrict__ et,
    int* __restrict__ gcoarse,
    const float* __restrict__ x, unsigned* __restrict__ x2,
    const float* __restrict__ basis1, const float* __restrict__ root1,
    __hip_bfloat16* __restrict__ WT1,
    const float* __restrict__ basis2, const float* __restrict__ root2,
    __hip_bfloat16* __restrict__ WT2,
    int* __restrict__ packed) {
  __shared__ __hip_bfloat16 tile[16][256];   // 8 KB (make_w)
  __shared__ int hist[NHI];                  // (P1)
  int bid = blockIdx.x;
  int tid = threadIdx.x;

  if (bid < NS_BLK) {                   // --- P1: coarse histogram ---
    if (tid < NHI) hist[tid] = 0;
    __syncthreads();
    int start = bid * CH, end = start + CH;
    for (int i = start + tid; i < end; i += 256) {
      int dst = ei[N_EDGES + i];
      atomicAdd(&hist[dst >> 8], 1);    // LDS atomic
    }
    __syncthreads();
    if (tid < NHI && hist[tid] > 0) atomicAdd(&gcoarse[tid], hist[tid]);
    return;
  }
  bid -= NS_BLK;
  if (bid < CB4) {                      // --- convert x -> bf16 (4 uints/thr) ---
    int idx = (bid * 256 + tid) * 4;    // exact: CB4*1024 == N*128
    const float* px = x + (size_t)idx * 2;
    float4 a = *(const float4*)(px);
    float4 b = *(const float4*)(px + 4);
    uint4 o;
    o.x = (unsigned)f2bu(a.x) | ((unsigned)f2bu(a.y) << 16);
    o.y = (unsigned)f2bu(a.z) | ((unsigned)f2bu(a.w) << 16);
    o.z = (unsigned)f2bu(b.x) | ((unsigned)f2bu(b.y) << 16);
    o.w = (unsigned)f2bu(b.z) | ((unsigned)f2bu(b.w) << 16);
    *(uint4*)(x2 + idx) = o;
    return;
  }
  bid -= CB4;
  if (bid < 2 * WKB) {                  // --- weight build (both layers) ---
    const float* basis = (bid < WKB) ? basis1 : basis2;
    const float* root  = (bid < WKB) ? root1 : root2;
    __hip_bfloat16* WT = (bid < WKB) ? WT1 : WT2;
    int wb = (bid < WKB) ? bid : bid - WKB;
    int k0 = wb * 64;
#pragma unroll
    for (int pass = 0; pass < 4; pass++) {
      int kp = k0 + pass * 16;
#pragma unroll
      for (int r = 0; r < 16; r++) {
        int k = kp + r;
        const float* srow = (k < KZ)
            ? basis + ((size_t)(k & 3) * D + (k >> 2)) * D
            : root + (size_t)(k - KZ) * D;
        tile[r][tid] = __float2bfloat16(srow[tid]);
      }
      __syncthreads();
      __hip_bfloat16* dst = WT + (size_t)tid * KT + kp;
#pragma unroll
      for (int c = 0; c < 2; c++) {
        union { short s[8]; int4 v; } u;
#pragma unroll
        for (int r = 0; r < 8; r++)
          u.s[r] = *reinterpret_cast<short*>(&tile[c * 8 + r][tid]);
        *(int4*)(dst + c * 8) = u.v;
      }
      __syncthreads();
    }
    return;
  }
  bid -= 2 * WKB;
  {                                     // --- dummy-fill packed (4 ints/thr) ---
    int i = (bid * 256 + tid) * 4;
    if (i < CAP) {                      // CAP % 4 == 0 -> full int4 valid
      int4 f = make_int4(DUMMY_P, DUMMY_P, DUMMY_P, DUMMY_P);
      *(int4*)(packed + i) = f;
    }
  }
}

// ---------------------------------------------------------------------------
// 2. P2: exclusive prefix of coarse counts -> gbase; init running cursors.
// ---------------------------------------------------------------------------
__global__ __launch_bounds__(256) void coarse_prefix_kernel(
    const int* __restrict__ gcoarse, int* __restrict__ gbase,
    int* __restrict__ gcur) {
  __shared__ int sd[256];
  int tid = threadIdx.x;
  int v = (tid < NHI) ? gcoarse[tid] : 0;
  sd[tid] = v;
  __syncthreads();
  for (int off = 1; off < 256; off <<= 1) {
    int t = (tid >= off) ? sd[tid - off] : 0;
    __syncthreads();
    sd[tid] += t;
    __syncthreads();
  }
  if (tid < NHI) {
    int b = sd[tid] - v;
    gbase[tid] = b;
    gcur[tid] = b;
  }
}

// ---------------------------------------------------------------------------
// 3. P3: coarse scatter. Per-block LDS hist -> one range-claim atomic per
//    bin -> scatter edges as 27-bit words src | rt<<16 | (dst&255)<<19.
// ---------------------------------------------------------------------------
__global__ __launch_bounds__(256) void coarse_scatter_kernel(
    const int* __restrict__ ei, const int* __restrict__ et,
    int* __restrict__ gcur, int* __restrict__ coarse) {
  __shared__ int hist[NHI];
  __shared__ int lbase[NHI];
  __shared__ int lcnt[NHI];
  int bid = blockIdx.x;
  int tid = threadIdx.x;
  if (tid < NHI) { hist[tid] = 0; lcnt[tid] = 0; }
  __syncthreads();
  int start = bid * CH, end = start + CH;
  for (int i = start + tid; i < end; i += 256)
    atomicAdd(&hist[ei[N_EDGES + i] >> 8], 1);
  __syncthreads();
  if (tid < NHI) lbase[tid] = atomicAdd(&gcur[tid], hist[tid]);
  __syncthreads();
  for (int i = start + tid; i < end; i += 256) {
    int src = ei[i];
    int dst = ei[N_EDGES + i];
    int rt  = et[i];
    int bin = dst >> 8;
    int rank = atomicAdd(&lcnt[bin], 1);   // LDS atomic
    coarse[lbase[bin] + rank] = src | (rt << 16) | ((dst & 255) << 19);
  }
}

// ---------------------------------------------------------------------------
// 4. P4a: per coarse bucket: fine hist over 256x8 keys (LDS), write cnt,
//    padded per-node degrees + local exclusive prefix, bucket total.
// ---------------------------------------------------------------------------
__global__ __launch_bounds__(256) void fine_hist_kernel(
    const int* __restrict__ coarse, const int* __restrict__ gbase,
    const int* __restrict__ gcoarse, int* __restrict__ cnt,
    int* __restrict__ lestart, int* __restrict__ btot) {
  __shared__ int c2[256 * R_REL];   // 8 KB fine histogram
  __shared__ int sd[256];
  int b = blockIdx.x;
  int tid = threadIdx.x;
#pragma unroll
  for (int k = tid; k < 256 * R_REL; k += 256) c2[k] = 0;
  __syncthreads();
  int base = gbase[b], n_e = gcoarse[b];
  for (int i = tid; i < n_e; i += 256) {
    int e = coarse[base + i];
    int key = ((e >> 19) & 255) * R_REL + ((e >> 16) & 7);
    atomicAdd(&c2[key], 1);
  }
  __syncthreads();
  // write cnt for winv
  int nodebase = b * 256;
#pragma unroll
  for (int k = tid; k < 256 * R_REL; k += 256) {
    int n = nodebase + (k >> 3);
    if (n < N_NODES) cnt[n * R_REL + (k & 7)] = c2[k];
  }
  // padded degree + prefix (thread tid owns node nodebase+tid)
  int d = 0;
#pragma unroll
  for (int r = 0; r < R_REL; r++) d += c2[tid * R_REL + r];
  int dp = (d + 7) & ~7;
  sd[tid] = dp;
  __syncthreads();
  for (int off = 1; off < 256; off <<= 1) {
    int t = (tid >= off) ? sd[tid - off] : 0;
    __syncthreads();
    sd[tid] += t;
    __syncthreads();
  }
  lestart[b * 256 + tid] = sd[tid] - dp;
  if (tid == 255) btot[b] = sd[255];
}

// ---------------------------------------------------------------------------
// 5. P4b: prefix of per-bucket padded totals -> bbase; estart[N] = total.
// ---------------------------------------------------------------------------
__global__ __launch_bounds__(256) void btot_prefix_kernel(
    const int* __restrict__ btot, int* __restrict__ bbase,
    int* __restrict__ estart) {
  __shared__ int sd[256];
  int tid = threadIdx.x;
  int v = (tid < NHI) ? btot[tid] : 0;
  sd[tid] = v;
  __syncthreads();
  for (int off = 1; off < 256; off <<= 1) {
    int t = (tid >= off) ? sd[tid - off] : 0;
    __syncthreads();
    sd[tid] += t;
    __syncthreads();
  }
  if (tid < NHI) bbase[tid] = sd[tid] - v;
  if (tid == NHI - 1) estart[N_NODES] = sd[tid];
}

// ---------------------------------------------------------------------------
// 6. P4c fused with winv: estart[n] = bbase[n>>8] + lestart[n]; wtab build.
// ---------------------------------------------------------------------------
__global__ __launch_bounds__(256) void finalize_kernel(
    const int* __restrict__ bbase, const int* __restrict__ lestart,
    int* __restrict__ estart, const int* __restrict__ cnt,
    const float* __restrict__ comp1, float4* __restrict__ wtab1,
    const float* __restrict__ comp2, float4* __restrict__ wtab2) {
  int bid = blockIdx.x;
  int tid = threadIdx.x;
  if (bid < NB) {                       // --- estart ---
    int n = bid * 256 + tid;
    if (n < N_NODES) estart[n] = bbase[n >> 8] + lestart[n];
    return;
  }
  bid -= NB;
  {                                     // --- winv (both layers) ---
    const float* comp = (bid < WB) ? comp1 : comp2;
    float4* wtab = (bid < WB) ? wtab1 : wtab2;
    int lb = (bid < WB) ? bid : bid - WB;
    int idx = lb * 256 + tid;           // exact: WB*256 == N*WSTRIDE
    int r = idx & (WSTRIDE - 1);
    int n = idx >> 4;
    float4 w = make_float4(0.f, 0.f, 0.f, 0.f);
    if (r < R_REL) {
      int c = cnt[n * R_REL + r];
      float inv = 1.0f / (float)(c > 0 ? c : 1);
      w.x = comp[r * BASES + 0] * inv;
      w.y = comp[r * BASES + 1] * inv;
      w.z = comp[r * BASES + 2] * inv;
      w.w = comp[r * BASES + 3] * inv;
    }
    wtab[idx] = w;
  }
}

// ---------------------------------------------------------------------------
// 7. P5: final scatter into padded packed layout (LDS rank counters; pad
//    slots keep the prefilled DUMMY_P).
// ---------------------------------------------------------------------------
__global__ __launch_bounds__(256) void fine_scatter_kernel(
    const int* __restrict__ coarse, const int* __restrict__ gbase,
    const int* __restrict__ gcoarse, const int* __restrict__ bbase,
    const int* __restrict__ lestart, int* __restrict__ packed) {
  __shared__ int lest[256];
  __shared__ int lcur[256];
  int b = blockIdx.x;
  int tid = threadIdx.x;
  lest[tid] = lestart[b * 256 + tid];
  lcur[tid] = 0;
  __syncthreads();
  int base = gbase[b], n_e = gcoarse[b];
  int sb = bbase[b];
  for (int i = tid; i < n_e; i += 256) {
    int e = coarse[base + i];
    int lo = (e >> 19) & 255;
    int rank = atomicAdd(&lcur[lo], 1);   // LDS atomic
    packed[sb + lest[lo] + rank] = (e & 0xFFFF) | (((e >> 16) & 7) << 20);
  }
}

// ---------------------------------------------------------------------------
// 8. Aggregate into basis space. WAVE per node (4/block). All wave-uniform
//    work (edge list, weights, row bases) forced onto the SCALAR pipe via
//    readfirstlane; buckets padded to x8 so the inner loop is branch- and
//    mask-free. Per-edge vector work: 1 global_load_dwordx2 (loop-invariant
//    voff), 4 unpack ops, 8 pk-fma.
// ---------------------------------------------------------------------------
__device__ inline float2 pfma(float s, float2 a, float2 c) {
  c.x = fmaf(s, a.x, c.x);
  c.y = fmaf(s, a.y, c.y);
  return c;
}

__device__ inline void edge_fma(float2 acc[BASES][2], uint2 v, float4 w) {
  float2 a01 = make_float2(bfu_lo(v.x), bfu_hi(v.x));
  float2 a23 = make_float2(bfu_lo(v.y), bfu_hi(v.y));
  acc[0][0] = pfma(w.x, a01, acc[0][0]); acc[0][1] = pfma(w.x, a23, acc[0][1]);
  acc[1][0] = pfma(w.y, a01, acc[1][0]); acc[1][1] = pfma(w.y, a23, acc[1][1]);
  acc[2][0] = pfma(w.z, a01, acc[2][0]); acc[2][1] = pfma(w.z, a23, acc[2][1]);
  acc[3][0] = pfma(w.w, a01, acc[3][0]); acc[3][1] = pfma(w.w, a23, acc[3][1]);
}

__global__ __launch_bounds__(256) void aggregate_kernel(
    const unsigned* __restrict__ x2,   // bf16 features as uint pairs [N][128]
    const int* __restrict__ packed,    // padded-x8 buckets
    const int* __restrict__ estart,    // padded offsets
    const float4* __restrict__ wtab,   // [N*16]; slot 8 = zero (dummy)
    __hip_bfloat16* __restrict__ zA)   // [N][KZ]
{
  int tid = threadIdx.x;
  int lane = tid & 63;
  int n = __builtin_amdgcn_readfirstlane(blockIdx.x * 4 + (tid >> 6));
  int s = __builtin_amdgcn_readfirstlane(estart[n]);
  int e = __builtin_amdgcn_readfirstlane(estart[n + 1]);
  const int voff = lane * 2;                         // uint index within row
  const float4* wt = wtab + (size_t)n * WSTRIDE;

  float2 acc[BASES][2] = {};

  for (int base = s; base < e; base += 8) {
    int4 q0 = *(const int4*)(packed + base);         // uniform addr -> s_load
    int4 q1 = *(const int4*)(packed + base + 4);
    int p0 = __builtin_amdgcn_readfirstlane(q0.x);
    int p1 = __builtin_amdgcn_readfirstlane(q0.y);
    int p2 = __builtin_amdgcn_readfirstlane(q0.z);
    int p3 = __builtin_amdgcn_readfirstlane(q0.w);
    int p4 = __builtin_amdgcn_readfirstlane(q1.x);
    int p5 = __builtin_amdgcn_readfirstlane(q1.y);
    int p6 = __builtin_amdgcn_readfirstlane(q1.z);
    int p7 = __builtin_amdgcn_readfirstlane(q1.w);
    // SGPR row bases; vector part is just base+voff
    const unsigned* r0 = x2 + ((size_t)(p0 & 0xFFFFF) << 7);
    const unsigned* r1 = x2 + ((size_t)(p1 & 0xFFFFF) << 7);
    const unsigned* r2 = x2 + ((size_t)(p2 & 0xFFFFF) << 7);
    const unsigned* r3 = x2 + ((size_t)(p3 & 0xFFFFF) << 7);
    const unsigned* r4 = x2 + ((size_t)(p4 & 0xFFFFF) << 7);
    const unsigned* r5 = x2 + ((size_t)(p5 & 0xFFFFF) << 7);
    const unsigned* r6 = x2 + ((size_t)(p6 & 0xFFFFF) << 7);
    const unsigned* r7 = x2 + ((size_t)(p7 & 0xFFFFF) << 7);
    uint2 v0 = *(const uint2*)(r0 + voff);
    uint2 v1 = *(const uint2*)(r1 + voff);
    uint2 v2 = *(const uint2*)(r2 + voff);
    uint2 v3 = *(const uint2*)(r3 + voff);
    uint2 v4 = *(const uint2*)(r4 + voff);
    uint2 v5 = *(const uint2*)(r5 + voff);
    uint2 v6 = *(const uint2*)(r6 + voff);
    uint2 v7 = *(const uint2*)(r7 + voff);
    float4 w0 = wt[p0 >> 20];                        // uniform -> s_load_x4
    float4 w1 = wt[p1 >> 20];
    float4 w2 = wt[p2 >> 20];
    float4 w3 = wt[p3 >> 20];
    float4 w4 = wt[p4 >> 20];
    float4 w5 = wt[p5 >> 20];
    float4 w6 = wt[p6 >> 20];
    float4 w7 = wt[p7 >> 20];
    edge_fma(acc, v0, w0);
    edge_fma(acc, v1, w1);
    edge_fma(acc, v2, w2);
    edge_fma(acc, v3, w3);
    edge_fma(acc, v4, w4);
    edge_fma(acc, v5, w5);
    edge_fma(acc, v6, w6);
    edge_fma(acc, v7, w7);
  }

  // store: k = (4*lane+j)*4 + b = 16*lane + 4*j + b -> 32 contiguous bytes
  union { short s[8]; int4 v; } u0, u1;
#pragma unroll
  for (int b = 0; b < BASES; b++) {
    u0.s[b]     = (short)f2bu(acc[b][0].x);
    u0.s[4 + b] = (short)f2bu(acc[b][0].y);
    u1.s[b]     = (short)f2bu(acc[b][1].x);
    u1.s[4 + b] = (short)f2bu(acc[b][1].y);
  }
  __hip_bfloat16* zrow = zA + (size_t)n * KZ;
  *(int4*)(zrow + 16 * lane) = u0.v;
  *(int4*)(zrow + 16 * lane + 8) = u1.v;
}

// ---------------------------------------------------------------------------
// 9. GEMM: C[M,256] = A[M,1280](bf16) @ WT^T + bias. BM=128, BN=256 (full N,
//    A read once), 512 threads / 8 waves, BK=32, global_load_lds staging.
//    A split: k<1024 from Az ([M][1024] aggregate), k>=1024 from Aself.
// ---------------------------------------------------------------------------
#define BM 128
#define BN 256
#define BK 32

template <bool RELU, typename OutT>
__global__ __launch_bounds__(512) void gemm_kernel(
    const __hip_bfloat16* __restrict__ Az,     // [M, KZ]
    const __hip_bfloat16* __restrict__ Aself,  // [M, D]
    const __hip_bfloat16* __restrict__ Bt,     // [256, KT]
    const float* __restrict__ bias, OutT* __restrict__ C, int M) {
  __shared__ __align__(16) __hip_bfloat16 As[BM * BK];  // 8 KB
  __shared__ __align__(16) __hip_bfloat16 Bs[BN * BK];  // 16 KB
  int tid = threadIdx.x;
  int m0 = blockIdx.x * BM;
  int wave = tid >> 6, lane = tid & 63;
  int wm = wave & 1, wn = wave >> 1;   // 2 x 4 wave grid, 64x64 tiles
  int l15 = lane & 15, quad = lane >> 4;

  int colS = (lane & 3) * 8;
  int rowA = wave * 16 + (lane >> 2);           // 0..127 across 8 waves
  int grA  = min(m0 + rowA, M - 1);             // clamp; epilogue masks tail
  const __hip_bfloat16* gAz = Az + (size_t)grA * KZ + colS;
  const __hip_bfloat16* gAs = Aself + (size_t)grA * D + colS;
  const __hip_bfloat16* gB0 = Bt + (size_t)(wave * 32 + (lane >> 2)) * KT + colS;
  const __hip_bfloat16* gB1 = gB0 + 16 * KT;
  __hip_bfloat16* lA  = As + wave * 512;
  __hip_bfloat16* lB0 = Bs + wave * 1024;
  __hip_bfloat16* lB1 = Bs + wave * 1024 + 512;

  f32x4 acc[4][4] = {};

  for (int k0 = 0; k0 < KT; k0 += BK) {
    const __hip_bfloat16* srcA = (k0 < KZ) ? (gAz + k0) : (gAs + (k0 - KZ));
    gload_lds16(lA, srcA);
    gload_lds16(lB0, gB0 + k0);
    gload_lds16(lB1, gB1 + k0);
    __syncthreads();

    bf16x8 af[4], bfr[4];
#pragma unroll
    for (int mt = 0; mt < 4; mt++)
      af[mt] = *(const bf16x8*)(As + (wm * 64 + mt * 16 + l15) * BK + quad * 8);
#pragma unroll
    for (int nt = 0; nt < 4; nt++)
      bfr[nt] = *(const bf16x8*)(Bs + (wn * 64 + nt * 16 + l15) * BK + quad * 8);
#pragma unroll
    for (int mt = 0; mt < 4; mt++)
#pragma unroll
      for (int nt = 0; nt < 4; nt++)
        acc[mt][nt] = __builtin_amdgcn_mfma_f32_16x16x32_bf16(
            af[mt], bfr[nt], acc[mt][nt], 0, 0, 0);
    __syncthreads();
  }

  // epilogue: C/D layout col = lane&15, row = quad*4 + reg
#pragma unroll
  for (int nt = 0; nt < 4; nt++) {
    int cg = wn * 64 + nt * 16 + l15;
    float bv = bias[cg];
#pragma unroll
    for (int mt = 0; mt < 4; mt++) {
#pragma unroll
      for (int r = 0; r < 4; r++) {
        int rg = m0 + wm * 64 + mt * 16 + quad * 4 + r;
        if (rg < M) {
          float v = acc[mt][nt][r] + bv;
          if (RELU) v = fmaxf(v, 0.f);
          store_out(C + (size_t)rg * D + cg, v);
        }
      }
    }
  }
}

// ---------------------------------------------------------------------------
// Launch
// ---------------------------------------------------------------------------
static inline char* carve(char*& p, size_t bytes) {
  char* r = p;
  p += (bytes + 255) & ~(size_t)255;
  return r;
}

extern "C" void kernel_launch(void* const* d_in, const int* in_sizes, int n_in,
                              void* d_out, int out_size, void* d_ws,
                              size_t ws_size, hipStream_t stream) {
  const float* x      = (const float*)d_in[0];
  const int*   ei     = (const int*)d_in[1];
  const int*   et     = (const int*)d_in[2];
  const float* basis1 = (const float*)d_in[3];
  const float* comp1  = (const float*)d_in[4];
  const float* root1  = (const float*)d_in[5];
  const float* bias1  = (const float*)d_in[6];
  const float* basis2 = (const float*)d_in[7];
  const float* comp2  = (const float*)d_in[8];
  const float* root2  = (const float*)d_in[9];
  const float* bias2  = (const float*)d_in[10];
  float* out = (float*)d_out;

  char* ws = (char*)d_ws;
  int* cnt     = (int*)carve(ws, (size_t)N_NODES * R_REL * 4);
  int* estart  = (int*)carve(ws, (size_t)(N_NODES + 1) * 4);
  int* coarse  = (int*)carve(ws, (size_t)N_EDGES * 4);
  int* lestart = (int*)carve(ws, (size_t)NHI * 256 * 4);
  int* gcoarse = (int*)carve(ws, 256 * 4);
  int* gbase   = (int*)carve(ws, 256 * 4);
  int* gcur    = (int*)carve(ws, 256 * 4);
  int* btot    = (int*)carve(ws, 256 * 4);
  int* bbase   = (int*)carve(ws, 256 * 4);
  int* packed  = (int*)carve(ws, (size_t)CAP * 4);
  float4* wtab1 = (float4*)carve(ws, (size_t)N_NODES * WSTRIDE * 16);
  float4* wtab2 = (float4*)carve(ws, (size_t)N_NODES * WSTRIDE * 16);
  __hip_bfloat16* WT1 = (__hip_bfloat16*)carve(ws, (size_t)D * KT * 2);
  __hip_bfloat16* WT2 = (__hip_bfloat16*)carve(ws, (size_t)D * KT * 2);
  unsigned* xb = (unsigned*)carve(ws, (size_t)N_NODES * D * 2);   // bf16 x
  __hip_bfloat16* h = (__hip_bfloat16*)carve(ws, (size_t)N_NODES * D * 2);
  __hip_bfloat16* zA = (__hip_bfloat16*)carve(ws, (size_t)N_NODES * KZ * 2);

  hipMemsetAsync(gcoarse, 0, 256 * 4, stream);

  prep_kernel<<<NS_BLK + CB4 + 2 * WKB + FB4, 256, 0, stream>>>(
      ei, et, gcoarse, x, xb, basis1, root1, WT1, basis2, root2, WT2, packed);
  coarse_prefix_kernel<<<1, 256, 0, stream>>>(gcoarse, gbase, gcur);
  coarse_scatter_kernel<<<NS_BLK, 256, 0, stream>>>(ei, et, gcur, coarse);
  fine_hist_kernel<<<NHI, 256, 0, stream>>>(coarse, gbase, gcoarse, cnt,
                                            lestart, btot);
  btot_prefix_kernel<<<1, 256, 0, stream>>>(btot, bbase, estart);
  finalize_kernel<<<NB + 2 * WB, 256, 0, stream>>>(bbase, lestart, estart, cnt,
                                                   comp1, wtab1, comp2, wtab2);
  fine_scatter_kernel<<<NHI, 256, 0, stream>>>(coarse, gbase, gcoarse, bbase,
                                               lestart, packed);

  dim3 ggrid((N_NODES + BM - 1) / BM, 1);  // 391 blocks, full N per block
  const int AB = (N_NODES + 3) / 4;        // 12500 blocks, wave per node

  // Layer 1
  aggregate_kernel<<<AB, 256, 0, stream>>>(xb, packed, estart, wtab1, zA);
  gemm_kernel<true, __hip_bfloat16><<<ggrid, 512, 0, stream>>>(
      zA, (const __hip_bfloat16*)xb, WT1, bias1, h, N_NODES);

  // Layer 2 (h is bf16 [N][256] — same packed-uint view as xb)
  aggregate_kernel<<<AB, 256, 0, stream>>>((const unsigned*)h, packed, estart,
                                           wtab2, zA);
  gemm_kernel<false, float><<<ggrid, 512, 0, stream>>>(
      zA, h, WT2, bias2, out, N_NODES);
}